// Round 4
// baseline (77.519 us; speedup 1.0000x reference)
//
#include <hip/hip_runtime.h>
#include <math.h>
#include <stdint.h>

// Problem constants (setup_inputs is fixed: B=64, T=512, H=768, L=400)
namespace {
constexpr int kB  = 64;
constexpr int kT  = 512;
constexpr int kH  = 768;
constexpr int kHm = 767;        // H-1 feature channels
constexpr int kL  = 400;        // max_label_length
constexpr int kC  = 16;         // k-chunks (parallel scan segments)
constexpr int kTC = kL / kC;    // 25 k-steps per chunk
constexpr int kBK = 16;         // staged k-rows per LDS batch
constexpr int kLwPad = kL + kBK + kTC; // pad so unconditional lw[k] reads are in-bounds
}

__device__ __forceinline__ float sigmoidf_(float x) {
  return 1.0f / (1.0f + expf(-x));
}

// One block per batch element b (512 threads):
//  - sigmoid of alpha channel for all T steps (parallel) + block-reduce sum
//  - lane 0 runs the 400-step scalar recurrence, emitting (w, m, sel) per k
//    (out_k = s + w*x ; s_new = sel*s + m*x) and, per chunk boundary 25c,
//    the rebuild start r0 = max(last fire strictly before 25c, 0).
__global__ __launch_bounds__(512) void k_rec(
    const float* __restrict__ hs, const int* __restrict__ labels,
    float* __restrict__ asum_ws, int* __restrict__ starts_ws,
    float4* __restrict__ wms) {
  __shared__ float a_lds[kT];
  __shared__ float red[kT];
  const int b = blockIdx.x;
  const int tid = threadIdx.x;

  float sig = sigmoidf_(hs[(size_t)b * kT * kH + (size_t)tid * kH + kHm]);
  a_lds[tid] = sig;
  red[tid] = sig;
  __syncthreads();
  for (int off = 256; off > 0; off >>= 1) {
    if (tid < off) red[tid] += red[tid + off];
    __syncthreads();
  }

  if (tid == 0) {
    const float as = red[0];
    asum_ws[b] = as;
    const int lab = labels[b];
    const float len = (float)(lab < kL ? lab : kL);
    const float scale = len / as;
    float a_r = 0.0f;
    int last_fire = -1;
    float4* wb = wms + b * kL;
    int* sb = starts_ws + b * kC;
    for (int c = 0; c < kC; ++c) {
      sb[c] = last_fire < 0 ? 0 : last_fire;  // replay from the fire itself
      const int kbase = c * kTC;
#pragma unroll
      for (int kk = 0; kk < kTC; ++kk) {
        const int k = kbase + kk;
        const float ak = a_lds[k] * scale;
        const float a_a = ak + a_r;
        const bool fired = (a_a >= 1.0f);
        const float w   = fired ? (1.0f - a_r) : ak;
        const float arn = fired ? (ak - (1.0f - a_r)) : a_a;  // exact ref expr
        const float m   = fired ? arn : ak;
        const float sel = fired ? 0.0f : 1.0f;
        wb[k] = make_float4(w, m, sel, 0.0f);
        if (fired) last_fire = k;
        a_r = arn;
      }
    }
  }
}

// Chunk-parallel scan with LDS-staged, double-buffered x tiles.
// Grid (3, B, kC), 256 threads (4 waves). Block (x,b,c) produces
// out[b, 25c..25c+24, h-tile] ; entry state is replayed from the last fire
// before 25c using the same fmaf chain (sel=0 at a fire resets the state,
// so the replay is bitwise-identical to the monolithic scan).
__global__ __launch_bounds__(256) void k_scan(
    const float* __restrict__ hs, const int* __restrict__ labels,
    const float* __restrict__ asum_ws, const int* __restrict__ starts_ws,
    const float4* __restrict__ wms, float* __restrict__ out) {
  __shared__ float4 lw[kLwPad];
  __shared__ float  xl[2][kBK][256];
  const int b   = blockIdx.y;
  const int c   = blockIdx.z;
  const int tid = threadIdx.x;
  const int h0  = blockIdx.x * 256;

  for (int i = tid; i < kL; i += 256) lw[i] = wms[b * kL + i];
  for (int i = kL + tid; i < kLwPad; i += 256) lw[i] = make_float4(0, 0, 0, 0);

  // n_hat = sum_b (len_b - alpha_sum_b)^2, once, in block (0,0,0)
  if (blockIdx.x == 0 && b == 0 && c == 0 && tid < kB) {
    const float as = asum_ws[tid];
    const int lab = labels[tid];
    const float len = (float)(lab < kL ? lab : kL);
    const float d = len - as;
    float v = d * d;
    for (int off = 32; off > 0; off >>= 1) v += __shfl_down(v, off, 64);
    if (tid == 0) out[(size_t)kB * kL * kHm] = v;
  }

  const int kb = c * kTC;        // first stored k
  const int ke = kb + kTC;       // one past last stored k
  const int r0 = __builtin_amdgcn_readfirstlane(starts_ws[b * kC + c]);

  const float* __restrict__ hb = hs + (size_t)b * kT * kH + h0;
  const int h = h0 + tid;
  const bool hok = (h < kHm);
  float* __restrict__ po = out + (size_t)b * kL * kHm + h;

  const int wv = tid >> 6;       // wave id 0..3
  const int ln = tid & 63;       // lane id

  // Stage kBK k-rows [k0, k0+kBK) into xl[buf]: one global_load_lds_dwordx4
  // per row per wave (64 lanes x 16 B = 1 KB row). Rows up to k0+2*kBK-1
  // <= 430 < T=512 stay in-bounds; h0+ln*4+3 <= 767 stays in-row.
  auto stage = [&](int buf, int k0) {
#pragma unroll
    for (int j = 0; j < kBK / 4; ++j) {
      const int rr = wv * (kBK / 4) + j;
      const float* src = hb + (size_t)(k0 + rr) * kH + ln * 4;
      __builtin_amdgcn_global_load_lds(
          (const __attribute__((address_space(1))) uint32_t*)src,
          (__attribute__((address_space(3))) uint32_t*)&xl[buf][rr][0],
          16, 0, 0);
    }
  };

  float s = 0.0f;
  int cur = 0;
  stage(0, r0);
  for (int k0 = r0; k0 < ke; k0 += kBK) {
    if (k0 + kBK < ke) stage(cur ^ 1, k0 + kBK);  // prefetch next batch
    __syncthreads();  // drains vmcnt: xl[cur] is ready

    // Batch the 16 LDS reads (stride-1 across threads: conflict-free).
    float xr[kBK];
#pragma unroll
    for (int kk = 0; kk < kBK; ++kk) xr[kk] = xl[cur][kk][tid];

#pragma unroll
    for (int kk = 0; kk < kBK; ++kk) {
      const int k = k0 + kk;
      if (k < ke) {                    // uniform guard
        const float4 c4 = lw[k];
        if (k >= kb) {                 // store phase (uniform)
          const float o = fmaf(c4.x, xr[kk], s);
          if (hok) po[(size_t)k * kHm] = o;
        }
        s = fmaf(c4.y, xr[kk], c4.z * s);  // rebuild & main share this chain
      }
    }
    __syncthreads();  // all waves done with xl[cur] before it is re-staged
    cur ^= 1;
  }
}

extern "C" void kernel_launch(void* const* d_in, const int* in_sizes, int n_in,
                              void* d_out, int out_size, void* d_ws, size_t ws_size,
                              hipStream_t stream) {
  const float* hs     = (const float*)d_in[0];
  const int*   labels = (const int*)d_in[1];
  float* out = (float*)d_out;

  // ws layout: [0,256) alpha_sum (64 f32); [256, 4352) starts (64 x 16 i32);
  // [8192, 8192+410KB) (w,m,sel,_) float4 per (b,k).
  float*  asum_ws   = (float*)d_ws;
  int*    starts_ws = (int*)((char*)d_ws + 256);
  float4* wms       = (float4*)((char*)d_ws + 8192);

  k_rec<<<kB, 512, 0, stream>>>(hs, labels, asum_ws, starts_ws, wms);
  k_scan<<<dim3((kHm + 255) / 256, kB, kC), 256, 0, stream>>>(
      hs, labels, asum_ws, starts_ws, wms, out);
}